// Round 2
// baseline (95.025 us; speedup 1.0000x reference)
//
#include <hip/hip_runtime.h>
#include <hip/hip_bf16.h>

#define S_LEN 127
#define NB    32
#define HDIM  256
#define DH    64
#define SCALE_F 0.125f

typedef __bf16 bf16x8 __attribute__((ext_vector_type(8)));
typedef float  f32x4  __attribute__((ext_vector_type(4)));

// ---------------------------------------------------------------------------
// Per-wave 16x16 output tile of out[M,256] = A[M,256] @ W[256,256]^T + bias.
// K = 256 -> 8 MFMA (16x16x32 bf16) steps. f32 inputs converted on the fly.
// A-frag: lane l holds row (l&15), k = (l>>4)*8 + j (verified layout, R1 pass).
// C/D: col = lane&15, row = (lane>>4)*4 + reg.
// ---------------------------------------------------------------------------
__device__ __forceinline__ void gemm16_tile(
    const float* __restrict__ A, const float* __restrict__ W,
    const float* __restrict__ bias, float* __restrict__ out,
    int row0, int col0)
{
  const int lane = threadIdx.x & 63;
  const int r  = lane & 15;
  const int ks = (lane >> 4) << 3;
  const float* Ab = A + (size_t)(row0 + r) * HDIM + ks;
  const float* Wb = W + (size_t)(col0 + r) * HDIM + ks;
  f32x4 acc = {};
#pragma unroll
  for (int kb = 0; kb < HDIM; kb += 32) {
    const float4 a0 = *(const float4*)(Ab + kb);
    const float4 a1 = *(const float4*)(Ab + kb + 4);
    const float4 w0 = *(const float4*)(Wb + kb);
    const float4 w1 = *(const float4*)(Wb + kb + 4);
    bf16x8 af, wf;
    af[0]=(__bf16)a0.x; af[1]=(__bf16)a0.y; af[2]=(__bf16)a0.z; af[3]=(__bf16)a0.w;
    af[4]=(__bf16)a1.x; af[5]=(__bf16)a1.y; af[6]=(__bf16)a1.z; af[7]=(__bf16)a1.w;
    wf[0]=(__bf16)w0.x; wf[1]=(__bf16)w0.y; wf[2]=(__bf16)w0.z; wf[3]=(__bf16)w0.w;
    wf[4]=(__bf16)w1.x; wf[5]=(__bf16)w1.y; wf[6]=(__bf16)w1.z; wf[7]=(__bf16)w1.w;
    acc = __builtin_amdgcn_mfma_f32_16x16x32_bf16(af, wf, acc, 0, 0, 0);
  }
  const int crow = (lane >> 4) * 4;
  const int ccol = lane & 15;
  const float bv = bias[col0 + ccol];
#pragma unroll
  for (int rg = 0; rg < 4; ++rg)
    out[(size_t)(row0 + crow + rg) * HDIM + col0 + ccol] = acc[rg] + bv;
}

// Fused q/k/v projection: grid (64, 16, 3), 256 threads (4 waves, 4 row-tiles).
__global__ __launch_bounds__(256) void gemm_qkv(
    const float* __restrict__ q_in, const float* __restrict__ k_in,
    const float* __restrict__ v_in,
    const float* __restrict__ Wq, const float* __restrict__ bq,
    const float* __restrict__ Wk, const float* __restrict__ bk,
    const float* __restrict__ Wv, const float* __restrict__ bv,
    float* __restrict__ qp, float* __restrict__ kp, float* __restrict__ vp)
{
  const int wv = threadIdx.x >> 6;
  const int tile = blockIdx.x * 4 + wv;
  if (tile >= 254) return;
  const float* A; const float* W; const float* bias; float* out;
  if (blockIdx.z == 0)      { A = q_in; W = Wq; bias = bq; out = qp; }
  else if (blockIdx.z == 1) { A = k_in; W = Wk; bias = bk; out = kp; }
  else                      { A = v_in; W = Wv; bias = bv; out = vp; }
  gemm16_tile(A, W, bias, out, tile * 16, blockIdx.y * 16);
}

// Output projection: grid (64, 16), 256 threads.
__global__ __launch_bounds__(256) void gemm_o(
    const float* __restrict__ A, const float* __restrict__ W,
    const float* __restrict__ bias, float* __restrict__ out)
{
  const int wv = threadIdx.x >> 6;
  const int tile = blockIdx.x * 4 + wv;
  if (tile >= 254) return;
  gemm16_tile(A, W, bias, out, tile * 16, blockIdx.y * 16);
}

// ---------------------------------------------------------------------------
// Fused sparse attention. One 256-thread block per (q, b).
// score[h,k] = sum_d (q[h,d]+eq[k,q,d]) * (k[k,h,d]+ek[q,k,d])
// Masked columns skipped exactly (exp(-1e5-max)==0 in f32 when any valid col
// exists); all-masked row -> exact uniform 1/127.
// ---------------------------------------------------------------------------
__global__ __launch_bounds__(256) void attn_kernel(
    const float* __restrict__ qp, const float* __restrict__ kp,
    const float* __restrict__ vp, const int* __restrict__ graph,
    const float* __restrict__ ekt, const float* __restrict__ evt,
    const float* __restrict__ eqt, float* __restrict__ xp)
{
  const int q = blockIdx.x;   // 0..126
  const int b = blockIdx.y;   // 0..31
  const int t = threadIdx.x;  // 0..255
  const int w = t >> 6;       // wave id 0..3
  const int l = t & 63;       // lane

  __shared__ int   s_list[S_LEN];
  __shared__ float s_attn[4][S_LEN];
  __shared__ int   s_cnt[2];

  // ---- build compacted valid-k list (waves 0,1; deterministic ballot) ----
  bool valid = false;
  const int k0 = w * 64 + l;
  if (w < 2 && k0 < S_LEN) {
    const int g = graph[((size_t)b * S_LEN + q) * S_LEN + k0];
    bool keep;
    if (q < 3 || k0 < 3) keep = true;
    else {
      const int blk = 3 + 2 * ((q - 3) >> 1);
      keep = (k0 >= blk) & (k0 < blk + 2);
    }
    valid = (g != 0) && keep;
  }
  const unsigned long long bal = __ballot(valid);
  if (w < 2 && l == 0) s_cnt[w] = (int)__popcll(bal);
  __syncthreads();
  int n = s_cnt[0] + s_cnt[1];
  if (valid) {
    const int pos = (int)__popcll(bal & ((1ull << l) - 1ull)) + (w ? s_cnt[0] : 0);
    s_list[pos] = k0;
  }
  __syncthreads();

  if (n == 0) {
    // all columns masked: softmax of uniform -1e5 -> exactly 1/127
    if (t < S_LEN) {
      s_list[t] = t;
      const float u = 1.0f / 127.0f;
      s_attn[0][t] = u; s_attn[1][t] = u; s_attn[2][t] = u; s_attn[3][t] = u;
    }
    n = S_LEN;
  } else {
    // ---- scores: 4 valid columns per iter (one per wave), pipelined ----
    const float* qrow = qp + ((size_t)b * S_LEN + q) * HDIM;
    const float  q0 = qrow[l], q1 = qrow[64 + l], q2 = qrow[128 + l], q3 = qrow[192 + l];
    const float* eqb = eqt + ((size_t)b * S_LEN * S_LEN + q) * DH;      // + k*S*DH + d
    const float* ekb = ekt + ((size_t)(b * S_LEN + q)) * S_LEN * DH;    // + k*DH + d
    const float* kpb = kp + (size_t)b * S_LEN * HDIM;

    float ceq = 0.f, cek = 0.f, ck0 = 0.f, ck1 = 0.f, ck2 = 0.f, ck3 = 0.f;
    if (w < n) {
      const int kk = s_list[w];
      ceq = eqb[(size_t)kk * (S_LEN * DH) + l];
      cek = ekb[kk * DH + l];
      const float* kr = kpb + (size_t)kk * HDIM;
      ck0 = kr[l]; ck1 = kr[64 + l]; ck2 = kr[128 + l]; ck3 = kr[192 + l];
    }
    for (int i0 = 0; i0 < n; i0 += 4) {
      const int i = i0 + w;
      // prefetch next iteration before the dependent shuffle chain
      float neq = 0.f, nek = 0.f, nk0 = 0.f, nk1 = 0.f, nk2 = 0.f, nk3 = 0.f;
      const int j = i + 4;
      if (j < n) {
        const int kk = s_list[j];
        neq = eqb[(size_t)kk * (S_LEN * DH) + l];
        nek = ekb[kk * DH + l];
        const float* kr = kpb + (size_t)kk * HDIM;
        nk0 = kr[l]; nk1 = kr[64 + l]; nk2 = kr[128 + l]; nk3 = kr[192 + l];
      }
      float p0 = (q0 + ceq) * (ck0 + cek);
      float p1 = (q1 + ceq) * (ck1 + cek);
      float p2 = (q2 + ceq) * (ck2 + cek);
      float p3 = (q3 + ceq) * (ck3 + cek);
#pragma unroll
      for (int off = 32; off; off >>= 1) {
        p0 += __shfl_xor(p0, off, 64);
        p1 += __shfl_xor(p1, off, 64);
        p2 += __shfl_xor(p2, off, 64);
        p3 += __shfl_xor(p3, off, 64);
      }
      if (i < n && l < 4) {
        const float s = (l == 0) ? p0 : (l == 1) ? p1 : (l == 2) ? p2 : p3;
        s_attn[l][i] = s * SCALE_F;
      }
      ceq = neq; cek = nek; ck0 = nk0; ck1 = nk1; ck2 = nk2; ck3 = nk3;
    }
    __syncthreads();

    // ---- softmax per head: wave w handles head w over n compacted scores ----
    {
      const float v0 = (l < n) ? s_attn[w][l] : -INFINITY;
      const float v1 = (64 + l < n) ? s_attn[w][64 + l] : -INFINITY;
      float mx = fmaxf(v0, v1);
#pragma unroll
      for (int off = 32; off; off >>= 1) mx = fmaxf(mx, __shfl_xor(mx, off, 64));
      const float e0 = (l < n) ? expf(v0 - mx) : 0.f;
      const float e1 = (64 + l < n) ? expf(v1 - mx) : 0.f;
      float sm = e0 + e1;
#pragma unroll
      for (int off = 32; off; off >>= 1) sm += __shfl_xor(sm, off, 64);
      const float inv = 1.0f / sm;
      if (l < n) s_attn[w][l] = e0 * inv;
      if (64 + l < n) s_attn[w][64 + l] = e1 * inv;
    }
  }
  __syncthreads();

  // ---- output: x[h=w, d=l] = sum_k attn * (v[k,h,d] + ev[q,k,d]) ----
  // unroll-4, dual accumulators: batch 8 independent loads per iteration.
  {
    const float* evb = evt + ((size_t)(b * S_LEN + q)) * S_LEN * DH;
    const float* vbp = vp + (size_t)b * S_LEN * HDIM + w * DH;
    float acc0 = 0.f, acc1 = 0.f;
    int i = 0;
    for (; i + 4 <= n; i += 4) {
      const int ka = s_list[i], kb2 = s_list[i + 1];
      const int kc = s_list[i + 2], kd = s_list[i + 3];
      const float aa = s_attn[w][i],     ab = s_attn[w][i + 1];
      const float ac = s_attn[w][i + 2], ad = s_attn[w][i + 3];
      const float va = vbp[(size_t)ka * HDIM + l],  ea = evb[ka * DH + l];
      const float vb2 = vbp[(size_t)kb2 * HDIM + l], eb = evb[kb2 * DH + l];
      const float vc = vbp[(size_t)kc * HDIM + l],  ec = evb[kc * DH + l];
      const float vd = vbp[(size_t)kd * HDIM + l],  ed = evb[kd * DH + l];
      acc0 += aa * (va + ea) + ab * (vb2 + eb);
      acc1 += ac * (vc + ec) + ad * (vd + ed);
    }
    for (; i < n; ++i) {
      const int kk = s_list[i];
      acc0 += s_attn[w][i] * (vbp[(size_t)kk * HDIM + l] + evb[kk * DH + l]);
    }
    xp[((size_t)b * S_LEN + q) * HDIM + t] = acc0 + acc1;
  }
}

extern "C" void kernel_launch(void* const* d_in, const int* in_sizes, int n_in,
                              void* d_out, int out_size, void* d_ws, size_t ws_size,
                              hipStream_t stream) {
  const float* query = (const float*)d_in[0];
  const float* key   = (const float*)d_in[1];
  const float* value = (const float*)d_in[2];
  const int*   graph = (const int*)d_in[3];
  const float* ekt   = (const float*)d_in[4];  // edge_key   [B,S,S,D]
  const float* evt   = (const float*)d_in[5];  // edge_value [B,S,S,D]
  const float* eqt   = (const float*)d_in[6];  // edge_query [B,S,S,D]
  const float* Wq = (const float*)d_in[7];  const float* bq = (const float*)d_in[8];
  const float* Wk = (const float*)d_in[9];  const float* bk = (const float*)d_in[10];
  const float* Wv = (const float*)d_in[11]; const float* bv = (const float*)d_in[12];
  const float* Wo = (const float*)d_in[13]; const float* bo = (const float*)d_in[14];
  float* out = (float*)d_out;

  const size_t NTOK = (size_t)NB * S_LEN;        // 4064 rows
  float* qp = (float*)d_ws;
  float* kp = qp + NTOK * HDIM;
  float* vp = kp + NTOK * HDIM;
  float* xp = vp + NTOK * HDIM;

  gemm_qkv<<<dim3(64, 16, 3), 256, 0, stream>>>(query, key, value,
                                                Wq, bq, Wk, bk, Wv, bv,
                                                qp, kp, vp);
  attn_kernel<<<dim3(S_LEN, NB), 256, 0, stream>>>(qp, kp, vp, graph,
                                                   ekt, evt, eqt, xp);
  gemm_o<<<dim3(64, 16), 256, 0, stream>>>(xp, Wo, bo, out);
}